// Round 1
// baseline (18152.100 us; speedup 1.0000x reference)
//
#include <hip/hip_runtime.h>
#include <hip/hip_bf16.h>
#include <math.h>

// Problem dims (fixed)
#define B_ 4
#define L_ 4096
#define C_ 1024
#define H_ 16
#define D_ 64
#define C3_ (3 * C_)          // 3072
#define EPS_ 1e-6f
#define SM_SCALE 0.125f       // D^-0.5

// ---------------------------------------------------------------------------
// GEMM: C[m,n] = sum_k A[m,k] * Bmat[n,k] (+ bias[n])
// A: MxK row-major, Bmat: NxK row-major (i.e. C = A @ B^T), C: MxN row-major.
// BM=BN=64, BK=16, 256 threads, 4x4 micro-tile per thread.
// All dims here divide the tile sizes exactly (M=16384, N in {3072,1024}, K=1024).
// ---------------------------------------------------------------------------
__global__ __launch_bounds__(256)
void gemm_nt_kernel(const float* __restrict__ A, const float* __restrict__ Bm,
                    const float* __restrict__ bias, float* __restrict__ C,
                    int M, int N, int K) {
  // +4 pad keeps 16B alignment for float4 LDS reads while breaking bank stride
  __shared__ float As[16][64 + 4];
  __shared__ float Bs[16][64 + 4];

  const int tid = threadIdx.x;
  const int m0 = blockIdx.y * 64;
  const int n0 = blockIdx.x * 64;

  const int lrow = tid >> 2;          // 0..63
  const int lc4  = (tid & 3) * 4;     // 0,4,8,12
  const int tx = tid & 15;            // output col group
  const int ty = tid >> 4;            // output row group

  float acc[4][4] = {};

  const float* Ap = A + (size_t)(m0 + lrow) * K + lc4;
  const float* Bp = Bm + (size_t)(n0 + lrow) * K + lc4;

  for (int k0 = 0; k0 < K; k0 += 16) {
    float4 a = *(const float4*)(Ap + k0);
    float4 b = *(const float4*)(Bp + k0);
    __syncthreads();  // previous iter's LDS reads done before overwrite
    As[lc4 + 0][lrow] = a.x; As[lc4 + 1][lrow] = a.y;
    As[lc4 + 2][lrow] = a.z; As[lc4 + 3][lrow] = a.w;
    Bs[lc4 + 0][lrow] = b.x; Bs[lc4 + 1][lrow] = b.y;
    Bs[lc4 + 2][lrow] = b.z; Bs[lc4 + 3][lrow] = b.w;
    __syncthreads();
#pragma unroll
    for (int k = 0; k < 16; ++k) {
      float4 av = *(const float4*)&As[k][ty * 4];
      float4 bv = *(const float4*)&Bs[k][tx * 4];
      float am[4] = {av.x, av.y, av.z, av.w};
      float bn[4] = {bv.x, bv.y, bv.z, bv.w};
#pragma unroll
      for (int i = 0; i < 4; ++i)
#pragma unroll
        for (int j = 0; j < 4; ++j)
          acc[i][j] += am[i] * bn[j];
    }
  }

  float4 bb = make_float4(0.f, 0.f, 0.f, 0.f);
  if (bias) bb = *(const float4*)(bias + n0 + tx * 4);
#pragma unroll
  for (int i = 0; i < 4; ++i) {
    float4 r;
    r.x = acc[i][0] + bb.x; r.y = acc[i][1] + bb.y;
    r.z = acc[i][2] + bb.z; r.w = acc[i][3] + bb.w;
    *(float4*)(C + (size_t)(m0 + ty * 4 + i) * N + n0 + tx * 4) = r;
  }
}

// ---------------------------------------------------------------------------
// Fused RMSNorm + RoPE, in place on the qkv buffer (q and k sections only).
// One wave per (b,l,h) row; lane = d (D=64). rotate_half partner = lane ^ 32.
// ---------------------------------------------------------------------------
__global__ __launch_bounds__(256)
void normrope_kernel(float* __restrict__ qkv,
                     const float* __restrict__ q_scale,
                     const float* __restrict__ k_scale,
                     const float* __restrict__ cosT,
                     const float* __restrict__ sinT) {
  const int wave = threadIdx.x >> 6;
  const int lane = threadIdx.x & 63;
  const long long rowId = (long long)blockIdx.x * 4 + wave;  // 0 .. 2*B*L*H-1
  const int NR = B_ * L_ * H_;
  if (rowId >= 2LL * NR) return;
  const int isK = rowId >= NR;
  int r = (int)(rowId - (isK ? NR : 0));
  const int h = r & (H_ - 1);
  const int l = (r >> 4) & (L_ - 1);
  const int b = r >> 16;  // / (L_*H_)

  float* p = qkv + (size_t)(b * L_ + l) * C3_ + (isK ? C_ : 0) + h * D_ + lane;
  float v = *p;

  float ss = v * v;
#pragma unroll
  for (int off = 32; off; off >>= 1) ss += __shfl_xor(ss, off);
  const float inv = rsqrtf(ss * (1.0f / 64.0f) + EPS_);

  const float* sc = isK ? k_scale : q_scale;
  float t = v * inv * sc[lane];
  float partner = __shfl_xor(t, 32);
  float rot = (lane < 32) ? -partner : partner;
  float c = cosT[l * D_ + lane];
  float s = sinT[l * D_ + lane];
  *p = t * c + rot * s;
}

// ---------------------------------------------------------------------------
// Flash attention, fp32. One block = 256 query rows of one (b,h); one thread
// owns one query row. K/V staged in LDS in 32-key tiles; score/PV inner loops
// read K/V with wave-uniform addresses (LDS broadcast, conflict-free).
// Online softmax with per-tile max + rescale.
// ---------------------------------------------------------------------------
#define QB 256
#define KB 32

__global__ __launch_bounds__(256)
void attn_kernel(const float* __restrict__ qkv, float* __restrict__ ctx) {
  __shared__ float Ks[KB][D_];
  __shared__ float Vs[KB][D_];

  const int bid = blockIdx.x;
  const int qc = bid & 15;           // L_/QB = 16 chunks
  const int h  = (bid >> 4) & (H_ - 1);
  const int b  = bid >> 8;
  const int tid = threadIdx.x;
  const int row = qc * QB + tid;

  const float* qp = qkv + (size_t)(b * L_ + row) * C3_ + h * D_;
  float q[D_];
#pragma unroll
  for (int d4 = 0; d4 < D_ / 4; ++d4) {
    float4 t = *(const float4*)(qp + d4 * 4);
    q[d4 * 4 + 0] = t.x * SM_SCALE; q[d4 * 4 + 1] = t.y * SM_SCALE;
    q[d4 * 4 + 2] = t.z * SM_SCALE; q[d4 * 4 + 3] = t.w * SM_SCALE;
  }

  float o[D_] = {};
  float m = -1e30f, lsum = 0.f;

  const size_t kbase = (size_t)(b * L_) * C3_ + C_ + h * D_;
  const size_t vbase = kbase + C_;

  for (int k0 = 0; k0 < L_; k0 += KB) {
    __syncthreads();  // previous tile's LDS reads done
    // stage KB x 64 floats of K and V: 512 float4 each over 256 threads
#pragma unroll
    for (int i = 0; i < (KB * D_ / 4) / 256; ++i) {
      int f = i * 256 + tid;
      int j = f >> 4, c4 = (f & 15) * 4;
      size_t roff = (size_t)(k0 + j) * C3_ + c4;
      *(float4*)&Ks[j][c4] = *(const float4*)(qkv + kbase + roff);
      *(float4*)&Vs[j][c4] = *(const float4*)(qkv + vbase + roff);
    }
    __syncthreads();

    float s[KB];
#pragma unroll
    for (int j = 0; j < KB; ++j) {
      float acc = 0.f;
#pragma unroll
      for (int d4 = 0; d4 < D_ / 4; ++d4) {
        float4 kk = *(const float4*)&Ks[j][d4 * 4];
        acc += q[d4 * 4 + 0] * kk.x + q[d4 * 4 + 1] * kk.y +
               q[d4 * 4 + 2] * kk.z + q[d4 * 4 + 3] * kk.w;
      }
      s[j] = acc;
    }

    float tmax = s[0];
#pragma unroll
    for (int j = 1; j < KB; ++j) tmax = fmaxf(tmax, s[j]);
    const float mn = fmaxf(m, tmax);
    const float corr = __expf(m - mn);
    lsum *= corr;
#pragma unroll
    for (int d = 0; d < D_; ++d) o[d] *= corr;

#pragma unroll
    for (int j = 0; j < KB; ++j) {
      const float p = __expf(s[j] - mn);
      lsum += p;
#pragma unroll
      for (int d4 = 0; d4 < D_ / 4; ++d4) {
        float4 vv = *(const float4*)&Vs[j][d4 * 4];
        o[d4 * 4 + 0] += p * vv.x; o[d4 * 4 + 1] += p * vv.y;
        o[d4 * 4 + 2] += p * vv.z; o[d4 * 4 + 3] += p * vv.w;
      }
    }
    m = mn;
  }

  const float invl = 1.0f / lsum;
  float* cp = ctx + (size_t)(b * L_ + row) * C_ + h * D_;
#pragma unroll
  for (int d4 = 0; d4 < D_ / 4; ++d4) {
    float4 r;
    r.x = o[d4 * 4 + 0] * invl; r.y = o[d4 * 4 + 1] * invl;
    r.z = o[d4 * 4 + 2] * invl; r.w = o[d4 * 4 + 3] * invl;
    *(float4*)(cp + d4 * 4) = r;
  }
}

// ---------------------------------------------------------------------------
extern "C" void kernel_launch(void* const* d_in, const int* in_sizes, int n_in,
                              void* d_out, int out_size, void* d_ws, size_t ws_size,
                              hipStream_t stream) {
  const float* x       = (const float*)d_in[0];
  const float* W_qkv   = (const float*)d_in[1];
  const float* q_scale = (const float*)d_in[2];
  const float* k_scale = (const float*)d_in[3];
  const float* W_proj  = (const float*)d_in[4];
  const float* b_proj  = (const float*)d_in[5];
  const float* cosT    = (const float*)d_in[6];
  const float* sinT    = (const float*)d_in[7];
  float* out = (float*)d_out;

  float* qkv = (float*)d_ws;                              // B*L*3C = 192 MiB
  float* ctx = qkv + (size_t)B_ * L_ * C3_;               // B*L*C  =  64 MiB

  const int M = B_ * L_;  // 16384

  // 1) qkv = x @ W_qkv^T
  {
    dim3 grid(C3_ / 64, M / 64);
    gemm_nt_kernel<<<grid, 256, 0, stream>>>(x, W_qkv, nullptr, qkv, M, C3_, C_);
  }
  // 2) RMSNorm + RoPE in place on q,k
  {
    int rows = 2 * B_ * L_ * H_;
    normrope_kernel<<<rows / 4, 256, 0, stream>>>(qkv, q_scale, k_scale, cosT, sinT);
  }
  // 3) attention -> ctx
  {
    int blocks = B_ * H_ * (L_ / QB);  // 1024
    attn_kernel<<<blocks, 256, 0, stream>>>(qkv, ctx);
  }
  // 4) out = ctx @ W_proj^T + b_proj
  {
    dim3 grid(C_ / 64, M / 64);
    gemm_nt_kernel<<<grid, 256, 0, stream>>>(ctx, W_proj, b_proj, out, M, C_, C_);
  }
}

// Round 2
// 3526.786 us; speedup vs baseline: 5.1469x; 5.1469x over previous
//
#include <hip/hip_runtime.h>
#include <hip/hip_bf16.h>
#include <math.h>

// Problem dims (fixed)
#define B_ 4
#define L_ 4096
#define C_ 1024
#define H_ 16
#define D_ 64
#define C3_ (3 * C_)          // 3072
#define EPS_ 1e-6f
// D^-0.5 * log2(e): fold into Q so softmax uses native exp2
#define QK_SCALE 0.18033688011112042f

typedef __attribute__((ext_vector_type(8))) short short8_t;
typedef __attribute__((ext_vector_type(4))) short short4_t;
typedef __attribute__((ext_vector_type(4))) float f32x4;

__device__ __forceinline__ short f2bf(float f) {
  __bf16 h = (__bf16)f;                 // RNE; compiler can pair into v_cvt_pk_bf16_f32
  union { __bf16 b; short s; } u; u.b = h;
  return u.s;
}

__device__ __forceinline__ short8_t pack8(float4 a, float4 b, float sc) {
  short8_t f;
  f[0] = f2bf(a.x * sc); f[1] = f2bf(a.y * sc);
  f[2] = f2bf(a.z * sc); f[3] = f2bf(a.w * sc);
  f[4] = f2bf(b.x * sc); f[5] = f2bf(b.y * sc);
  f[6] = f2bf(b.z * sc); f[7] = f2bf(b.w * sc);
  return f;
}

// ---------------------------------------------------------------------------
// fp32 GEMM: C = A @ B^T (+bias). Unchanged from baseline (correct, ~1.6ms
// combined; convert to MFMA next round once attention absmax is validated).
// ---------------------------------------------------------------------------
__global__ __launch_bounds__(256)
void gemm_nt_kernel(const float* __restrict__ A, const float* __restrict__ Bm,
                    const float* __restrict__ bias, float* __restrict__ C,
                    int M, int N, int K) {
  __shared__ float As[16][64 + 4];
  __shared__ float Bs[16][64 + 4];

  const int tid = threadIdx.x;
  const int m0 = blockIdx.y * 64;
  const int n0 = blockIdx.x * 64;

  const int lrow = tid >> 2;
  const int lc4  = (tid & 3) * 4;
  const int tx = tid & 15;
  const int ty = tid >> 4;

  float acc[4][4] = {};

  const float* Ap = A + (size_t)(m0 + lrow) * K + lc4;
  const float* Bp = Bm + (size_t)(n0 + lrow) * K + lc4;

  for (int k0 = 0; k0 < K; k0 += 16) {
    float4 a = *(const float4*)(Ap + k0);
    float4 b = *(const float4*)(Bp + k0);
    __syncthreads();
    As[lc4 + 0][lrow] = a.x; As[lc4 + 1][lrow] = a.y;
    As[lc4 + 2][lrow] = a.z; As[lc4 + 3][lrow] = a.w;
    Bs[lc4 + 0][lrow] = b.x; Bs[lc4 + 1][lrow] = b.y;
    Bs[lc4 + 2][lrow] = b.z; Bs[lc4 + 3][lrow] = b.w;
    __syncthreads();
#pragma unroll
    for (int k = 0; k < 16; ++k) {
      float4 av = *(const float4*)&As[k][ty * 4];
      float4 bv = *(const float4*)&Bs[k][tx * 4];
      float am[4] = {av.x, av.y, av.z, av.w};
      float bn[4] = {bv.x, bv.y, bv.z, bv.w};
#pragma unroll
      for (int i = 0; i < 4; ++i)
#pragma unroll
        for (int j = 0; j < 4; ++j)
          acc[i][j] += am[i] * bn[j];
    }
  }

  float4 bb = make_float4(0.f, 0.f, 0.f, 0.f);
  if (bias) bb = *(const float4*)(bias + n0 + tx * 4);
#pragma unroll
  for (int i = 0; i < 4; ++i) {
    float4 r;
    r.x = acc[i][0] + bb.x; r.y = acc[i][1] + bb.y;
    r.z = acc[i][2] + bb.z; r.w = acc[i][3] + bb.w;
    *(float4*)(C + (size_t)(m0 + ty * 4 + i) * N + n0 + tx * 4) = r;
  }
}

// ---------------------------------------------------------------------------
// Fused RMSNorm + RoPE, in place on qkv (q,k). One wave per (b,l,h) row.
// ---------------------------------------------------------------------------
__global__ __launch_bounds__(256)
void normrope_kernel(float* __restrict__ qkv,
                     const float* __restrict__ q_scale,
                     const float* __restrict__ k_scale,
                     const float* __restrict__ cosT,
                     const float* __restrict__ sinT) {
  const int wave = threadIdx.x >> 6;
  const int lane = threadIdx.x & 63;
  const long long rowId = (long long)blockIdx.x * 4 + wave;
  const int NR = B_ * L_ * H_;
  if (rowId >= 2LL * NR) return;
  const int isK = rowId >= NR;
  int r = (int)(rowId - (isK ? NR : 0));
  const int h = r & (H_ - 1);
  const int l = (r >> 4) & (L_ - 1);
  const int b = r >> 16;

  float* p = qkv + (size_t)(b * L_ + l) * C3_ + (isK ? C_ : 0) + h * D_ + lane;
  float v = *p;

  float ss = v * v;
#pragma unroll
  for (int off = 32; off; off >>= 1) ss += __shfl_xor(ss, off);
  const float inv = rsqrtf(ss * (1.0f / 64.0f) + EPS_);

  const float* sc = isK ? k_scale : q_scale;
  float t = v * inv * sc[lane];
  float partner = __shfl_xor(t, 32);
  float rot = (lane < 32) ? -partner : partner;
  float c = cosT[l * D_ + lane];
  float s = sinT[l * D_ + lane];
  *p = t * c + rot * s;
}

// ---------------------------------------------------------------------------
// bf16 MFMA flash attention.
// Block = 256 threads = 4 waves; each wave owns 32 q-rows (2 strips of 16).
// Per 32-key tile: K staged bf16 [32][72] (natural), V staged bf16 transposed
// [64][36]; QK^T via mfma_f32_16x16x32_bf16 (A=Q regs, B=K^T from LDS);
// online softmax in fp32 on the D-tile layout (row=(lane>>4)*4+reg,
// col=lane&15); P repacked bf16 through per-wave LDS tile to A-frag layout;
// PV via MFMA with V^T B-frags. exp2-based softmax (scale folded into Q).
// ---------------------------------------------------------------------------
#define KB 32

__global__ __launch_bounds__(256)
void attn_mfma_kernel(const float* __restrict__ qkv, float* __restrict__ ctx) {
  __shared__ short Ks[KB][72];      // bf16 K tile; 144B rows (16B aligned)
  __shared__ short Vt[D_][36];      // bf16 V^T tile; 72B rows (8B aligned)
  __shared__ short Pt[4][16][40];   // per-wave P tile; 80B rows (16B aligned)

  // XCD-aware swizzle: 2048 blocks, 8 XCDs -> blocks sharing (b,h) K/V stay
  // on one XCD's L2.
  const int bid0 = blockIdx.x;
  const int bid = (bid0 & 7) * 256 + (bid0 >> 3);
  const int qc = bid & 31;                 // L/128 = 32 q-chunks
  const int hh = (bid >> 5) & (H_ - 1);
  const int b  = bid >> 9;

  const int tid = threadIdx.x;
  const int w    = tid >> 6;
  const int lane = tid & 63;
  const int l15  = lane & 15;
  const int lg   = lane >> 4;

  const size_t bL = (size_t)b * L_;
  const int qrow0 = qc * 128 + w * 32;

  // Q fragments (A-operand layout: row = lane&15, k = (lane>>4)*8+i),
  // scale folded in. qf[strip][k-chunk], k-chunk covers 32 of D=64.
  short8_t qf[2][2];
#pragma unroll
  for (int s = 0; s < 2; ++s)
#pragma unroll
    for (int kc = 0; kc < 2; ++kc) {
      const float* qp = qkv + (bL + qrow0 + s * 16 + l15) * C3_ + hh * D_ + kc * 32 + lg * 8;
      float4 x0 = *(const float4*)qp;
      float4 x1 = *(const float4*)(qp + 4);
      qf[s][kc] = pack8(x0, x1, QK_SCALE);
    }

  f32x4 O[2][4];
  float m_[2][4], l_[2][4];
#pragma unroll
  for (int s = 0; s < 2; ++s) {
#pragma unroll
    for (int nb = 0; nb < 4; ++nb) O[s][nb] = (f32x4){0.f, 0.f, 0.f, 0.f};
#pragma unroll
    for (int r = 0; r < 4; ++r) { m_[s][r] = -1e30f; l_[s][r] = 0.f; }
  }

  const size_t kbase = bL * C3_ + C_ + hh * D_;

  for (int k0 = 0; k0 < L_; k0 += KB) {
    __syncthreads();  // prior tile's LDS reads complete
    {
      // stage: thread t handles key j = t>>3, dim-chunk c8 = t&7 (8 dims)
      const int j = tid >> 3, c8 = tid & 7;
      const float* kp = qkv + kbase + (size_t)(k0 + j) * C3_ + c8 * 8;
      float4 a0 = *(const float4*)kp;
      float4 a1 = *(const float4*)(kp + 4);
      *(short8_t*)&Ks[j][c8 * 8] = pack8(a0, a1, 1.0f);
      const float* vp = kp + C_;
      float4 b0 = *(const float4*)vp;
      float4 b1 = *(const float4*)(vp + 4);
      short vv[8];
      vv[0] = f2bf(b0.x); vv[1] = f2bf(b0.y); vv[2] = f2bf(b0.z); vv[3] = f2bf(b0.w);
      vv[4] = f2bf(b1.x); vv[5] = f2bf(b1.y); vv[6] = f2bf(b1.z); vv[7] = f2bf(b1.w);
#pragma unroll
      for (int i = 0; i < 8; ++i) Vt[c8 * 8 + i][j] = vv[i];
    }
    __syncthreads();

    // K^T B-frags: col = key = lane&15 (+16 per key-block), k = kc*32+(lane>>4)*8
    short8_t kf[2][2];
#pragma unroll
    for (int kb = 0; kb < 2; ++kb)
#pragma unroll
      for (int kc = 0; kc < 2; ++kc)
        kf[kb][kc] = *(short8_t*)&Ks[kb * 16 + l15][kc * 32 + lg * 8];

    short8_t pa[2];
#pragma unroll
    for (int s = 0; s < 2; ++s) {
      f32x4 a0 = (f32x4){0.f, 0.f, 0.f, 0.f};
      f32x4 a1 = (f32x4){0.f, 0.f, 0.f, 0.f};
#pragma unroll
      for (int kc = 0; kc < 2; ++kc) {
        a0 = __builtin_amdgcn_mfma_f32_16x16x32_bf16(qf[s][kc], kf[0][kc], a0, 0, 0, 0);
        a1 = __builtin_amdgcn_mfma_f32_16x16x32_bf16(qf[s][kc], kf[1][kc], a1, 0, 0, 0);
      }
      // online softmax; D row = lg*4+r, col(key) = l15; reduce across 16 lanes
#pragma unroll
      for (int r = 0; r < 4; ++r) {
        float rm = fmaxf(a0[r], a1[r]);
        rm = fmaxf(rm, __shfl_xor(rm, 1));
        rm = fmaxf(rm, __shfl_xor(rm, 2));
        rm = fmaxf(rm, __shfl_xor(rm, 4));
        rm = fmaxf(rm, __shfl_xor(rm, 8));
        const float mo = m_[s][r];
        const float mn = fmaxf(mo, rm);
        const float corr = exp2f(mo - mn);
        m_[s][r] = mn;
        const float p0 = exp2f(a0[r] - mn);
        const float p1 = exp2f(a1[r] - mn);
        float rs = p0 + p1;
        rs += __shfl_xor(rs, 1);
        rs += __shfl_xor(rs, 2);
        rs += __shfl_xor(rs, 4);
        rs += __shfl_xor(rs, 8);
        l_[s][r] = l_[s][r] * corr + rs;
#pragma unroll
        for (int nb = 0; nb < 4; ++nb) O[s][nb][r] *= corr;
        // P write: row = q-in-strip = lg*4+r, col = key (conflict-free pattern)
        Pt[w][lg * 4 + r][l15] = f2bf(p0);
        Pt[w][lg * 4 + r][16 + l15] = f2bf(p1);
      }
      // P A-frag: row = l15, keys lg*8..+8 (same-wave RAW; HW/compiler waits)
      pa[s] = *(short8_t*)&Pt[w][l15][lg * 8];
    }

    // V^T B-frags (col = dim = nb*16+l15, k = key = lg*8+i) + PV MFMA
#pragma unroll
    for (int nb = 0; nb < 4; ++nb) {
      const short* vr = &Vt[nb * 16 + l15][lg * 8];
      short4_t vlo = *(const short4_t*)vr;
      short4_t vhi = *(const short4_t*)(vr + 4);
      short8_t vf;
      vf[0] = vlo[0]; vf[1] = vlo[1]; vf[2] = vlo[2]; vf[3] = vlo[3];
      vf[4] = vhi[0]; vf[5] = vhi[1]; vf[6] = vhi[2]; vf[7] = vhi[3];
      O[0][nb] = __builtin_amdgcn_mfma_f32_16x16x32_bf16(pa[0], vf, O[0][nb], 0, 0, 0);
      O[1][nb] = __builtin_amdgcn_mfma_f32_16x16x32_bf16(pa[1], vf, O[1][nb], 0, 0, 0);
    }
  }

  // epilogue: O row = lg*4+r (matches softmax reg), col = nb*16+l15
#pragma unroll
  for (int s = 0; s < 2; ++s)
#pragma unroll
    for (int r = 0; r < 4; ++r) {
      const float inv = 1.0f / l_[s][r];
      float* cp = ctx + (bL + qrow0 + s * 16 + lg * 4 + r) * C_ + hh * D_ + l15;
#pragma unroll
      for (int nb = 0; nb < 4; ++nb)
        cp[nb * 16] = O[s][nb][r] * inv;
    }
}

// ---------------------------------------------------------------------------
extern "C" void kernel_launch(void* const* d_in, const int* in_sizes, int n_in,
                              void* d_out, int out_size, void* d_ws, size_t ws_size,
                              hipStream_t stream) {
  const float* x       = (const float*)d_in[0];
  const float* W_qkv   = (const float*)d_in[1];
  const float* q_scale = (const float*)d_in[2];
  const float* k_scale = (const float*)d_in[3];
  const float* W_proj  = (const float*)d_in[4];
  const float* b_proj  = (const float*)d_in[5];
  const float* cosT    = (const float*)d_in[6];
  const float* sinT    = (const float*)d_in[7];
  float* out = (float*)d_out;

  float* qkv = (float*)d_ws;                              // B*L*3C = 192 MiB
  float* ctx = qkv + (size_t)B_ * L_ * C3_;               // B*L*C  =  64 MiB

  const int M = B_ * L_;  // 16384

  // 1) qkv = x @ W_qkv^T
  {
    dim3 grid(C3_ / 64, M / 64);
    gemm_nt_kernel<<<grid, 256, 0, stream>>>(x, W_qkv, nullptr, qkv, M, C3_, C_);
  }
  // 2) RMSNorm + RoPE in place on q,k
  {
    int rows = 2 * B_ * L_ * H_;
    normrope_kernel<<<rows / 4, 256, 0, stream>>>(qkv, q_scale, k_scale, cosT, sinT);
  }
  // 3) attention -> ctx (bf16 MFMA flash)
  {
    int blocks = B_ * H_ * (L_ / 128);  // 2048
    attn_mfma_kernel<<<blocks, 256, 0, stream>>>(qkv, ctx);
  }
  // 4) out = ctx @ W_proj^T + b_proj
  {
    dim3 grid(C_ / 64, M / 64);
    gemm_nt_kernel<<<grid, 256, 0, stream>>>(ctx, W_proj, b_proj, out, M, C_, C_);
  }
}

// Round 3
// 1562.525 us; speedup vs baseline: 11.6172x; 2.2571x over previous
//
#include <hip/hip_runtime.h>
#include <hip/hip_bf16.h>
#include <math.h>

// Problem dims (fixed)
#define B_ 4
#define L_ 4096
#define C_ 1024
#define H_ 16
#define D_ 64
#define C3_ 3072
#define EPS_ 1e-6f
// D^-0.5 * log2(e): folded into Q so softmax uses exp2
#define QK_SCALE 0.18033688011112042f

typedef unsigned short u16;
typedef __attribute__((ext_vector_type(8))) short short8_t;
typedef __attribute__((ext_vector_type(4))) short short4_t;
typedef __attribute__((ext_vector_type(4))) float f32x4;

typedef const __attribute__((address_space(1))) void* gas_t;
typedef __attribute__((address_space(3))) void* las_t;

// async global->LDS, 16B per lane; LDS dest = wave-uniform base + lane*16
__device__ __forceinline__ void glds16(const void* g, void* l) {
  __builtin_amdgcn_global_load_lds((gas_t)g, (las_t)l, 16, 0, 0);
}

__device__ __forceinline__ u16 f2bf_u(float f) {
  __bf16 h = (__bf16)f;
  union { __bf16 b; u16 s; } u; u.b = h; return u.s;
}
__device__ __forceinline__ float bf2f_u(u16 s) {
  union { unsigned u; float f; } u2; u2.u = ((unsigned)s) << 16; return u2.f;
}

// ---------------------------------------------------------------------------
// fp32 -> (bf16 hi, bf16 lo) split: x = hi + lo + O(2^-18 x)
// ---------------------------------------------------------------------------
__global__ __launch_bounds__(256)
void split_kernel(const float* __restrict__ x, u16* __restrict__ hi,
                  u16* __restrict__ lo, int n4) {
  int i = blockIdx.x * 256 + threadIdx.x;
  const int stride = gridDim.x * 256;
  for (; i < n4; i += stride) {
    float4 v = ((const float4*)x)[i];
    short4_t h4, l4;
    h4[0] = f2bf_u(v.x); l4[0] = f2bf_u(v.x - bf2f_u(h4[0]));
    h4[1] = f2bf_u(v.y); l4[1] = f2bf_u(v.y - bf2f_u(h4[1]));
    h4[2] = f2bf_u(v.z); l4[2] = f2bf_u(v.z - bf2f_u(h4[2]));
    h4[3] = f2bf_u(v.w); l4[3] = f2bf_u(v.w - bf2f_u(h4[3]));
    ((short4_t*)hi)[i] = h4;
    ((short4_t*)lo)[i] = l4;
  }
}

// ---------------------------------------------------------------------------
// bf16x3 MFMA GEMM: C = A @ B^T (+bias), fp32-quality via hi/lo split.
// A: [M][K], B: [N][K], both pre-split bf16. 128x128 tile, BK=32, 4 waves 2x2.
// MODE 0: Cf fp32 row-major + bias (proj). MODE 1: scatter bf16 head-major
// into outq/outk/outv [B][H][L][D] (QKV epilogue).
// Tiles [128][32] bf16 linear: frag ds_read_b128 covers a full contiguous 1KB
// per wave -> conflict-free; glds staging is linear (no swizzle needed).
// ---------------------------------------------------------------------------
template <int MODE>
__global__ __launch_bounds__(256)
void gemm_bx3_kernel(const u16* __restrict__ Ah, const u16* __restrict__ Al,
                     const u16* __restrict__ Bh, const u16* __restrict__ Bl,
                     const float* __restrict__ bias, float* __restrict__ Cf,
                     u16* __restrict__ outq, u16* __restrict__ outk,
                     u16* __restrict__ outv, int M, int N, int K) {
  __shared__ __align__(16) u16 S[4][128][32];   // Ah,Al,Bh,Bl tiles: 32KB

  const int tid = threadIdx.x;
  const int m0 = blockIdx.y * 128;
  const int n0 = blockIdx.x * 128;
  const int w = tid >> 6, lane = tid & 63;
  const int wr = w >> 1, wc = w & 1;
  const int l15 = lane & 15, lg = lane >> 4;

  f32x4 acc[4][4];
#pragma unroll
  for (int i = 0; i < 4; ++i)
#pragma unroll
    for (int j = 0; j < 4; ++j) acc[i][j] = (f32x4){0.f, 0.f, 0.f, 0.f};

  // staging: 512 16B-slots per tile; this thread covers slots tid, tid+256
  const int r0 = tid >> 2,         c0 = (tid & 3) * 8;
  const int r1 = (256 + tid) >> 2, c1 = (tid & 3) * 8;   // (256+tid)&3 == tid&3
  char* const Sb = (char*)&S[0][0][0];
  const int woff = w * 1024;   // wave-uniform LDS offset

  for (int k0 = 0; k0 < K; k0 += 32) {
    __syncthreads();
    {
      const size_t a0 = (size_t)(m0 + r0) * K + k0 + c0;
      const size_t a1 = (size_t)(m0 + r1) * K + k0 + c1;
      const size_t b0 = (size_t)(n0 + r0) * K + k0 + c0;
      const size_t b1 = (size_t)(n0 + r1) * K + k0 + c1;
      glds16(Ah + a0, Sb + 0 * 8192 + 0 * 4096 + woff);
      glds16(Ah + a1, Sb + 0 * 8192 + 1 * 4096 + woff);
      glds16(Al + a0, Sb + 1 * 8192 + 0 * 4096 + woff);
      glds16(Al + a1, Sb + 1 * 8192 + 1 * 4096 + woff);
      glds16(Bh + b0, Sb + 2 * 8192 + 0 * 4096 + woff);
      glds16(Bh + b1, Sb + 2 * 8192 + 1 * 4096 + woff);
      glds16(Bl + b0, Sb + 3 * 8192 + 0 * 4096 + woff);
      glds16(Bl + b1, Sb + 3 * 8192 + 1 * 4096 + woff);
    }
    __syncthreads();   // compiler drains vmcnt before barrier

    short8_t af[2][4], bfr[2][4];
#pragma unroll
    for (int m = 0; m < 4; ++m) {
      const int row = wr * 64 + m * 16 + l15;
      af[0][m] = *(const short8_t*)(Sb + 0 * 8192 + row * 64 + lg * 16);
      af[1][m] = *(const short8_t*)(Sb + 1 * 8192 + row * 64 + lg * 16);
    }
#pragma unroll
    for (int n = 0; n < 4; ++n) {
      const int row = wc * 64 + n * 16 + l15;
      bfr[0][n] = *(const short8_t*)(Sb + 2 * 8192 + row * 64 + lg * 16);
      bfr[1][n] = *(const short8_t*)(Sb + 3 * 8192 + row * 64 + lg * 16);
    }
#pragma unroll
    for (int m = 0; m < 4; ++m)
#pragma unroll
      for (int n = 0; n < 4; ++n) {
        acc[m][n] = __builtin_amdgcn_mfma_f32_16x16x32_bf16(af[0][m], bfr[0][n], acc[m][n], 0, 0, 0);
        acc[m][n] = __builtin_amdgcn_mfma_f32_16x16x32_bf16(af[0][m], bfr[1][n], acc[m][n], 0, 0, 0);
        acc[m][n] = __builtin_amdgcn_mfma_f32_16x16x32_bf16(af[1][m], bfr[0][n], acc[m][n], 0, 0, 0);
      }
  }

  // epilogue. C frag: row = lg*4+r (+m*16), col = l15 (+n*16)
  if constexpr (MODE == 0) {
    float bb[4];
#pragma unroll
    for (int n = 0; n < 4; ++n) bb[n] = bias ? bias[n0 + wc * 64 + n * 16 + l15] : 0.f;
#pragma unroll
    for (int m = 0; m < 4; ++m)
#pragma unroll
      for (int r = 0; r < 4; ++r) {
        const int row = m0 + wr * 64 + m * 16 + lg * 4 + r;
        float* orow = Cf + (size_t)row * N + n0 + wc * 64 + l15;
#pragma unroll
        for (int n = 0; n < 4; ++n) orow[n * 16] = acc[m][n][r] + bb[n];
      }
  } else {
    // col block -> one tensor t, one head h per wave (64-col aligned)
    const int colbase = n0 + wc * 64;
    const int t = colbase >> 10;
    const int h = (colbase & 1023) >> 6;
    u16* const base = (t == 0) ? outq : (t == 1) ? outk : outv;
#pragma unroll
    for (int m = 0; m < 4; ++m)
#pragma unroll
      for (int r = 0; r < 4; ++r) {
        const int row = m0 + wr * 64 + m * 16 + lg * 4 + r;  // = b*L + l
        const int b = row >> 12, l = row & 4095;
        u16* dp = base + (((size_t)(b * H_ + h)) * L_ + l) * D_ + l15;
#pragma unroll
        for (int n = 0; n < 4; ++n) dp[n * 16] = f2bf_u(acc[m][n][r]);
      }
  }
}

// ---------------------------------------------------------------------------
// RMSNorm + RoPE in place on bf16 Qb/Kb ([B][H][L][D]); fp32 math.
// One wave per row; lane = d. QK_SCALE folded into Q.
// ---------------------------------------------------------------------------
__global__ __launch_bounds__(256)
void normrope2_kernel(u16* __restrict__ qb, u16* __restrict__ kb,
                      const float* __restrict__ q_scale,
                      const float* __restrict__ k_scale,
                      const float* __restrict__ cosT,
                      const float* __restrict__ sinT) {
  const int w = threadIdx.x >> 6, lane = threadIdx.x & 63;
  const int NR = B_ * H_ * L_;                    // 262144
  const int rid = blockIdx.x * 4 + w;             // 0 .. 2*NR-1
  const int isK = rid >= NR;
  const int r = rid - (isK ? NR : 0);
  const int l = r & (L_ - 1);

  u16* p = (isK ? kb : qb) + (size_t)r * D_ + lane;
  const float v = bf2f_u(*p);

  float ss = v * v;
#pragma unroll
  for (int off = 32; off; off >>= 1) ss += __shfl_xor(ss, off);
  const float inv = rsqrtf(ss * (1.0f / 64.0f) + EPS_);

  const float t = v * inv * (isK ? k_scale[lane] : q_scale[lane]);
  const float partner = __shfl_xor(t, 32);
  const float rot = (lane < 32) ? -partner : partner;
  float res = t * cosT[l * D_ + lane] + rot * sinT[l * D_ + lane];
  if (!isK) res *= QK_SCALE;
  *p = f2bf_u(res);
}

// ---------------------------------------------------------------------------
// V transpose: vb [B][H][L][D] bf16 -> vt [B][H][D][L] bf16. 64x64 tiles.
// ---------------------------------------------------------------------------
__global__ __launch_bounds__(256)
void vtrans_kernel(const u16* __restrict__ vb, u16* __restrict__ vt) {
  __shared__ __align__(16) u16 T[64][72];   // 72-pad: b128-aligned rows (144B)
  const int bh = blockIdx.y;
  const int l0 = blockIdx.x * 64;
  const int tid = threadIdx.x;
#pragma unroll
  for (int it = 0; it < 2; ++it) {
    const int idx = it * 256 + tid;
    const int l = idx >> 3, dc = idx & 7;
    short8_t v8 = *(const short8_t*)(vb + ((size_t)bh * L_ + l0 + l) * D_ + dc * 8);
#pragma unroll
    for (int j = 0; j < 8; ++j) T[dc * 8 + j][l] = (u16)v8[j];
  }
  __syncthreads();
#pragma unroll
  for (int it = 0; it < 2; ++it) {
    const int idx = it * 256 + tid;
    const int d = idx >> 3, q = idx & 7;
    short8_t o8 = *(const short8_t*)((const char*)&T[0][0] + d * 144 + q * 16);
    *(short8_t*)(vt + ((size_t)bh * D_ + d) * L_ + l0 + q * 8) = o8;
  }
}

// ---------------------------------------------------------------------------
// bf16 MFMA flash attention v2. 4 waves x 32 q-rows; KB=64 keys/tile.
// K tile [64][64] and V^T tile [64][64] staged via glds with XOR slot-swizzle
// (phys 16B-slot = logical ^ (row&7)), read back with the same XOR ->
// conflict-free ds_read_b128 frags and zero staging VALU.
// ---------------------------------------------------------------------------
__global__ __launch_bounds__(256)
void attn2_kernel(const u16* __restrict__ qb, const u16* __restrict__ kb,
                  const u16* __restrict__ vt, float* __restrict__ ctx) {
  __shared__ __align__(16) u16 Ks[64][64];      // 8KB, swizzled slots
  __shared__ __align__(16) u16 Vs[64][64];      // 8KB, Vt[dim][key], swizzled
  __shared__ __align__(16) u16 Pt[4][16][88];   // per-wave P; 176B rows

  const int bid0 = blockIdx.x;
  const int bid = (bid0 & 7) * 256 + (bid0 >> 3);   // XCD swizzle (2048 % 8 == 0)
  const int qc = bid & 31;
  const int h  = (bid >> 5) & (H_ - 1);
  const int b  = bid >> 9;
  const int bh = b * H_ + h;

  const int tid = threadIdx.x;
  const int w = tid >> 6, lane = tid & 63;
  const int l15 = lane & 15, lg = lane >> 4;
  const int qrow0 = qc * 128 + w * 32;

  // Q frags (scale pre-folded): A layout row=l15, k=lg*8+i
  short8_t qf[2][2];
#pragma unroll
  for (int s = 0; s < 2; ++s)
#pragma unroll
    for (int kc = 0; kc < 2; ++kc)
      qf[s][kc] = *(const short8_t*)(qb + ((size_t)bh * L_ + qrow0 + s * 16 + l15) * D_ + kc * 32 + lg * 8);

  f32x4 O[2][4];
  float m_[2][4], l_[2][4];
#pragma unroll
  for (int s = 0; s < 2; ++s) {
#pragma unroll
    for (int nb = 0; nb < 4; ++nb) O[s][nb] = (f32x4){0.f, 0.f, 0.f, 0.f};
#pragma unroll
    for (int r = 0; r < 4; ++r) { m_[s][r] = -1e30f; l_[s][r] = 0.f; }
  }

  const u16* const kbase = kb + (size_t)bh * L_ * D_;
  const u16* const vbase = vt + (size_t)bh * D_ * L_;
  const int swoff = w * 1024;

  for (int k0 = 0; k0 < L_; k0 += 64) {
    __syncthreads();
#pragma unroll
    for (int it = 0; it < 2; ++it) {
      const int idx = it * 256 + tid;
      const int row = idx >> 3, ps = idx & 7;
      const int ls = ps ^ (row & 7);   // inverse-swizzled global source
      glds16(kbase + (size_t)(k0 + row) * D_ + ls * 8, (char*)&Ks[0][0] + it * 4096 + swoff);
      glds16(vbase + (size_t)row * L_ + k0 + ls * 8,   (char*)&Vs[0][0] + it * 4096 + swoff);
    }
    __syncthreads();

    short8_t pa[2][2];
#pragma unroll
    for (int s = 0; s < 2; ++s) {
      f32x4 a[4];
#pragma unroll
      for (int kb_ = 0; kb_ < 4; ++kb_) a[kb_] = (f32x4){0.f, 0.f, 0.f, 0.f};
#pragma unroll
      for (int kb_ = 0; kb_ < 4; ++kb_) {
        const int row = kb_ * 16 + l15;
        const short8_t kf0 = *(const short8_t*)((const char*)&Ks[0][0] + row * 128 + ((lg ^ (row & 7)) * 16));
        const short8_t kf1 = *(const short8_t*)((const char*)&Ks[0][0] + row * 128 + (((4 + lg) ^ (row & 7)) * 16));
        a[kb_] = __builtin_amdgcn_mfma_f32_16x16x32_bf16(qf[s][0], kf0, a[kb_], 0, 0, 0);
        a[kb_] = __builtin_amdgcn_mfma_f32_16x16x32_bf16(qf[s][1], kf1, a[kb_], 0, 0, 0);
      }
      // online softmax: D row = lg*4+r, col(key) = kb_*16 + l15
#pragma unroll
      for (int r = 0; r < 4; ++r) {
        float rm = fmaxf(fmaxf(a[0][r], a[1][r]), fmaxf(a[2][r], a[3][r]));
        rm = fmaxf(rm, __shfl_xor(rm, 1));
        rm = fmaxf(rm, __shfl_xor(rm, 2));
        rm = fmaxf(rm, __shfl_xor(rm, 4));
        rm = fmaxf(rm, __shfl_xor(rm, 8));
        const float mo = m_[s][r];
        const float mn = fmaxf(mo, rm);
        const float corr = exp2f(mo - mn);
        m_[s][r] = mn;
        float p0 = exp2f(a[0][r] - mn), p1 = exp2f(a[1][r] - mn);
        float p2 = exp2f(a[2][r] - mn), p3 = exp2f(a[3][r] - mn);
        float rs = (p0 + p1) + (p2 + p3);
        rs += __shfl_xor(rs, 1);
        rs += __shfl_xor(rs, 2);
        rs += __shfl_xor(rs, 4);
        rs += __shfl_xor(rs, 8);
        l_[s][r] = l_[s][r] * corr + rs;
#pragma unroll
        for (int nb = 0; nb < 4; ++nb) O[s][nb][r] *= corr;
        u16* prow = &Pt[w][lg * 4 + r][0];
        prow[l15]      = f2bf_u(p0);
        prow[16 + l15] = f2bf_u(p1);
        prow[32 + l15] = f2bf_u(p2);
        prow[48 + l15] = f2bf_u(p3);
      }
      // P A-frag: row = l15, keys kc*32 + lg*8 (same-wave LDS RAW)
      pa[s][0] = *(const short8_t*)&Pt[w][l15][lg * 8];
      pa[s][1] = *(const short8_t*)&Pt[w][l15][32 + lg * 8];
    }

    // PV: B-frag col = dim = nb*16+l15, k = key = kc*32+lg*8+i
#pragma unroll
    for (int nb = 0; nb < 4; ++nb) {
      const int row = nb * 16 + l15;
#pragma unroll
      for (int kc = 0; kc < 2; ++kc) {
        const short8_t vf = *(const short8_t*)((const char*)&Vs[0][0] + row * 128 + (((kc * 4 + lg) ^ (row & 7)) * 16));
        O[0][nb] = __builtin_amdgcn_mfma_f32_16x16x32_bf16(pa[0][kc], vf, O[0][nb], 0, 0, 0);
        O[1][nb] = __builtin_amdgcn_mfma_f32_16x16x32_bf16(pa[1][kc], vf, O[1][nb], 0, 0, 0);
      }
    }
  }

  // epilogue: row = lg*4+r, col = nb*16+l15
#pragma unroll
  for (int s = 0; s < 2; ++s)
#pragma unroll
    for (int r = 0; r < 4; ++r) {
      const float inv = 1.0f / l_[s][r];
      float* cp = ctx + ((size_t)b * L_ + qrow0 + s * 16 + lg * 4 + r) * C_ + h * D_ + l15;
#pragma unroll
      for (int nb = 0; nb < 4; ++nb) cp[nb * 16] = O[s][nb][r] * inv;
    }
}

// ---------------------------------------------------------------------------
// ws layout (208MB total, <= 256MB proven budget):
// [0,32)   qb bf16      | reused after attn: ctx_hi
// [32,64)  kb bf16      | reused after attn: ctx_lo
// [64,96)  vb bf16
// [96,128) vt bf16 (V^T)
// [128,192) ctx fp32    | before attn: x_hi | x_lo
// [192,208) Wqkv hi/lo, Wproj hi/lo
// ---------------------------------------------------------------------------
extern "C" void kernel_launch(void* const* d_in, const int* in_sizes, int n_in,
                              void* d_out, int out_size, void* d_ws, size_t ws_size,
                              hipStream_t stream) {
  const float* x       = (const float*)d_in[0];
  const float* W_qkv   = (const float*)d_in[1];
  const float* q_scale = (const float*)d_in[2];
  const float* k_scale = (const float*)d_in[3];
  const float* W_proj  = (const float*)d_in[4];
  const float* b_proj  = (const float*)d_in[5];
  const float* cosT    = (const float*)d_in[6];
  const float* sinT    = (const float*)d_in[7];
  float* out = (float*)d_out;

  const int M = B_ * L_;                    // 16384
  const size_t NBLH = (size_t)M * C_;       // 16M elements

  u16* qb = (u16*)d_ws;
  u16* kb = qb + NBLH;
  u16* vb = kb + NBLH;
  u16* vt = vb + NBLH;
  float* ctx = (float*)((char*)d_ws + (size_t)128 * 1024 * 1024);
  u16* xh = (u16*)ctx;
  u16* xl = xh + NBLH;
  u16* wqh = (u16*)((char*)d_ws + (size_t)192 * 1024 * 1024);
  u16* wql = wqh + (size_t)C3_ * C_;
  u16* wph = wql + (size_t)C3_ * C_;
  u16* wpl = wph + (size_t)C_ * C_;
  u16* ch = qb;                             // ctx hi/lo reuse qb/kb space
  u16* cl = kb;

  // 1) splits
  split_kernel<<<2048, 256, 0, stream>>>(x, xh, xl, (int)(NBLH / 4));
  split_kernel<<<512, 256, 0, stream>>>(W_qkv, wqh, wql, C3_ * C_ / 4);
  split_kernel<<<512, 256, 0, stream>>>(W_proj, wph, wpl, C_ * C_ / 4);
  // 2) qkv = x @ W_qkv^T -> bf16 head-major qb/kb/vb
  {
    dim3 grid(C3_ / 128, M / 128);
    gemm_bx3_kernel<1><<<grid, 256, 0, stream>>>(xh, xl, wqh, wql, nullptr,
                                                 nullptr, qb, kb, vb, M, C3_, C_);
  }
  // 3) RMSNorm + RoPE in place (scale folded into q)
  normrope2_kernel<<<2 * B_ * H_ * L_ / 4, 256, 0, stream>>>(qb, kb, q_scale, k_scale, cosT, sinT);
  // 4) V transpose
  {
    dim3 grid(L_ / 64, B_ * H_);
    vtrans_kernel<<<grid, 256, 0, stream>>>(vb, vt);
  }
  // 5) attention -> ctx fp32
  attn2_kernel<<<B_ * H_ * (L_ / 128), 256, 0, stream>>>(qb, kb, vt, ctx);
  // 6) split ctx
  split_kernel<<<2048, 256, 0, stream>>>(ctx, ch, cl, (int)(NBLH / 4));
  // 7) out = ctx @ W_proj^T + b_proj
  {
    dim3 grid(C_ / 128, M / 128);
    gemm_bx3_kernel<0><<<grid, 256, 0, stream>>>(ch, cl, wph, wpl, b_proj, out,
                                                 nullptr, nullptr, nullptr, M, C_, C_);
  }
}

// Round 4
// 1300.358 us; speedup vs baseline: 13.9593x; 1.2016x over previous
//
#include <hip/hip_runtime.h>
#include <hip/hip_bf16.h>
#include <math.h>

// Problem dims (fixed)
#define B_ 4
#define L_ 4096
#define C_ 1024
#define H_ 16
#define D_ 64
#define C3_ 3072
#define EPS_ 1e-6f
// D^-0.5 * log2(e): folded into Q so softmax uses exp2
#define QK_SCALE 0.18033688011112042f

typedef unsigned short u16;
typedef __attribute__((ext_vector_type(8))) short short8_t;
typedef __attribute__((ext_vector_type(4))) short short4_t;
typedef __attribute__((ext_vector_type(4))) float f32x4;

typedef const __attribute__((address_space(1))) void* gas_t;
typedef __attribute__((address_space(3))) void* las_t;

// async global->LDS, 16B per lane; LDS dest = wave-uniform base + lane*16
__device__ __forceinline__ void glds16(const void* g, void* l) {
  __builtin_amdgcn_global_load_lds((gas_t)g, (las_t)l, 16, 0, 0);
}

__device__ __forceinline__ u16 f2bf_u(float f) {
  __bf16 h = (__bf16)f;
  union { __bf16 b; u16 s; } u; u.b = h; return u.s;
}
__device__ __forceinline__ float bf2f_u(u16 s) {
  union { unsigned u; float f; } u2; u2.u = ((unsigned)s) << 16; return u2.f;
}

// ---------------------------------------------------------------------------
// fp32 -> (bf16 hi, bf16 lo) split: x = hi + lo + O(2^-18 x)
// ---------------------------------------------------------------------------
__global__ __launch_bounds__(256)
void split_kernel(const float* __restrict__ x, u16* __restrict__ hi,
                  u16* __restrict__ lo, int n4) {
  int i = blockIdx.x * 256 + threadIdx.x;
  const int stride = gridDim.x * 256;
  for (; i < n4; i += stride) {
    float4 v = ((const float4*)x)[i];
    short4_t h4, l4;
    h4[0] = f2bf_u(v.x); l4[0] = f2bf_u(v.x - bf2f_u(h4[0]));
    h4[1] = f2bf_u(v.y); l4[1] = f2bf_u(v.y - bf2f_u(h4[1]));
    h4[2] = f2bf_u(v.z); l4[2] = f2bf_u(v.z - bf2f_u(h4[2]));
    h4[3] = f2bf_u(v.w); l4[3] = f2bf_u(v.w - bf2f_u(h4[3]));
    ((short4_t*)hi)[i] = h4;
    ((short4_t*)lo)[i] = l4;
  }
}

// ---------------------------------------------------------------------------
// bf16x3 MFMA GEMM: C = A @ B^T (+bias), fp32-quality via hi/lo split.
// Unchanged from round 3 (verified).
// ---------------------------------------------------------------------------
template <int MODE>
__global__ __launch_bounds__(256)
void gemm_bx3_kernel(const u16* __restrict__ Ah, const u16* __restrict__ Al,
                     const u16* __restrict__ Bh, const u16* __restrict__ Bl,
                     const float* __restrict__ bias, float* __restrict__ Cf,
                     u16* __restrict__ outq, u16* __restrict__ outk,
                     u16* __restrict__ outv, int M, int N, int K) {
  __shared__ __align__(16) u16 S[4][128][32];   // Ah,Al,Bh,Bl tiles: 32KB

  const int tid = threadIdx.x;
  const int m0 = blockIdx.y * 128;
  const int n0 = blockIdx.x * 128;
  const int w = tid >> 6, lane = tid & 63;
  const int wr = w >> 1, wc = w & 1;
  const int l15 = lane & 15, lg = lane >> 4;

  f32x4 acc[4][4];
#pragma unroll
  for (int i = 0; i < 4; ++i)
#pragma unroll
    for (int j = 0; j < 4; ++j) acc[i][j] = (f32x4){0.f, 0.f, 0.f, 0.f};

  const int r0 = tid >> 2,         c0 = (tid & 3) * 8;
  const int r1 = (256 + tid) >> 2, c1 = (tid & 3) * 8;
  char* const Sb = (char*)&S[0][0][0];
  const int woff = w * 1024;

  for (int k0 = 0; k0 < K; k0 += 32) {
    __syncthreads();
    {
      const size_t a0 = (size_t)(m0 + r0) * K + k0 + c0;
      const size_t a1 = (size_t)(m0 + r1) * K + k0 + c1;
      const size_t b0 = (size_t)(n0 + r0) * K + k0 + c0;
      const size_t b1 = (size_t)(n0 + r1) * K + k0 + c1;
      glds16(Ah + a0, Sb + 0 * 8192 + 0 * 4096 + woff);
      glds16(Ah + a1, Sb + 0 * 8192 + 1 * 4096 + woff);
      glds16(Al + a0, Sb + 1 * 8192 + 0 * 4096 + woff);
      glds16(Al + a1, Sb + 1 * 8192 + 1 * 4096 + woff);
      glds16(Bh + b0, Sb + 2 * 8192 + 0 * 4096 + woff);
      glds16(Bh + b1, Sb + 2 * 8192 + 1 * 4096 + woff);
      glds16(Bl + b0, Sb + 3 * 8192 + 0 * 4096 + woff);
      glds16(Bl + b1, Sb + 3 * 8192 + 1 * 4096 + woff);
    }
    __syncthreads();

    short8_t af[2][4], bfr[2][4];
#pragma unroll
    for (int m = 0; m < 4; ++m) {
      const int row = wr * 64 + m * 16 + l15;
      af[0][m] = *(const short8_t*)(Sb + 0 * 8192 + row * 64 + lg * 16);
      af[1][m] = *(const short8_t*)(Sb + 1 * 8192 + row * 64 + lg * 16);
    }
#pragma unroll
    for (int n = 0; n < 4; ++n) {
      const int row = wc * 64 + n * 16 + l15;
      bfr[0][n] = *(const short8_t*)(Sb + 2 * 8192 + row * 64 + lg * 16);
      bfr[1][n] = *(const short8_t*)(Sb + 3 * 8192 + row * 64 + lg * 16);
    }
#pragma unroll
    for (int m = 0; m < 4; ++m)
#pragma unroll
      for (int n = 0; n < 4; ++n) {
        acc[m][n] = __builtin_amdgcn_mfma_f32_16x16x32_bf16(af[0][m], bfr[0][n], acc[m][n], 0, 0, 0);
        acc[m][n] = __builtin_amdgcn_mfma_f32_16x16x32_bf16(af[0][m], bfr[1][n], acc[m][n], 0, 0, 0);
        acc[m][n] = __builtin_amdgcn_mfma_f32_16x16x32_bf16(af[1][m], bfr[0][n], acc[m][n], 0, 0, 0);
      }
  }

  if constexpr (MODE == 0) {
    float bb[4];
#pragma unroll
    for (int n = 0; n < 4; ++n) bb[n] = bias ? bias[n0 + wc * 64 + n * 16 + l15] : 0.f;
#pragma unroll
    for (int m = 0; m < 4; ++m)
#pragma unroll
      for (int r = 0; r < 4; ++r) {
        const int row = m0 + wr * 64 + m * 16 + lg * 4 + r;
        float* orow = Cf + (size_t)row * N + n0 + wc * 64 + l15;
#pragma unroll
        for (int n = 0; n < 4; ++n) orow[n * 16] = acc[m][n][r] + bb[n];
      }
  } else {
    const int colbase = n0 + wc * 64;
    const int t = colbase >> 10;
    const int h = (colbase & 1023) >> 6;
    u16* const base = (t == 0) ? outq : (t == 1) ? outk : outv;
#pragma unroll
    for (int m = 0; m < 4; ++m)
#pragma unroll
      for (int r = 0; r < 4; ++r) {
        const int row = m0 + wr * 64 + m * 16 + lg * 4 + r;  // = b*L + l
        const int b = row >> 12, l = row & 4095;
        u16* dp = base + (((size_t)(b * H_ + h)) * L_ + l) * D_ + l15;
#pragma unroll
        for (int n = 0; n < 4; ++n) dp[n * 16] = f2bf_u(acc[m][n][r]);
      }
  }
}

// ---------------------------------------------------------------------------
// RMSNorm + RoPE in place on bf16 Qb/Kb ([B][H][L][D]); QK_SCALE into Q.
// ---------------------------------------------------------------------------
__global__ __launch_bounds__(256)
void normrope2_kernel(u16* __restrict__ qb, u16* __restrict__ kb,
                      const float* __restrict__ q_scale,
                      const float* __restrict__ k_scale,
                      const float* __restrict__ cosT,
                      const float* __restrict__ sinT) {
  const int w = threadIdx.x >> 6, lane = threadIdx.x & 63;
  const int NR = B_ * H_ * L_;
  const int rid = blockIdx.x * 4 + w;
  const int isK = rid >= NR;
  const int r = rid - (isK ? NR : 0);
  const int l = r & (L_ - 1);

  u16* p = (isK ? kb : qb) + (size_t)r * D_ + lane;
  const float v = bf2f_u(*p);

  float ss = v * v;
#pragma unroll
  for (int off = 32; off; off >>= 1) ss += __shfl_xor(ss, off);
  const float inv = rsqrtf(ss * (1.0f / 64.0f) + EPS_);

  const float t = v * inv * (isK ? k_scale[lane] : q_scale[lane]);
  const float partner = __shfl_xor(t, 32);
  const float rot = (lane < 32) ? -partner : partner;
  float res = t * cosT[l * D_ + lane] + rot * sinT[l * D_ + lane];
  if (!isK) res *= QK_SCALE;
  *p = f2bf_u(res);
}

// ---------------------------------------------------------------------------
// V transpose: vb [B][H][L][D] -> vt [B][H][D][L] (bf16). 64x64 tiles.
// ---------------------------------------------------------------------------
__global__ __launch_bounds__(256)
void vtrans_kernel(const u16* __restrict__ vb, u16* __restrict__ vt) {
  __shared__ __align__(16) u16 T[64][72];
  const int bh = blockIdx.y;
  const int l0 = blockIdx.x * 64;
  const int tid = threadIdx.x;
#pragma unroll
  for (int it = 0; it < 2; ++it) {
    const int idx = it * 256 + tid;
    const int l = idx >> 3, dc = idx & 7;
    short8_t v8 = *(const short8_t*)(vb + ((size_t)bh * L_ + l0 + l) * D_ + dc * 8);
#pragma unroll
    for (int j = 0; j < 8; ++j) T[dc * 8 + j][l] = (u16)v8[j];
  }
  __syncthreads();
#pragma unroll
  for (int it = 0; it < 2; ++it) {
    const int idx = it * 256 + tid;
    const int d = idx >> 3, q = idx & 7;
    short8_t o8 = *(const short8_t*)((const char*)&T[0][0] + d * 144 + q * 16);
    *(short8_t*)(vt + ((size_t)bh * D_ + d) * L_ + l0 + q * 8) = o8;
  }
}

// ---------------------------------------------------------------------------
// bf16 MFMA flash attention v3: swapped QK^T (scores lane-local per q-row),
// defer-max (THR=8, exp2-domain), per-lane deferred l-sum, KB=128.
// 4 waves x 32 q-rows. K [128][64] / V^T [64][128] staged via glds with XOR
// slot-swizzle. P packed to LDS as b64 writes, read back as b128 A-frags.
// Epilogue writes ctx as bf16 hi/lo (split fused).
// ---------------------------------------------------------------------------
__global__ __launch_bounds__(256)
void attn3_kernel(const u16* __restrict__ qb, const u16* __restrict__ kb,
                  const u16* __restrict__ vt, u16* __restrict__ ch,
                  u16* __restrict__ cl) {
  __shared__ __align__(16) u16 Ks[128][64];     // 16KB, swizzled slots
  __shared__ __align__(16) u16 Vs[64][128];     // 16KB, V^T, swizzled slots
  __shared__ __align__(16) u16 Pt[4][16][136];  // per-wave P [q][key], 272B rows

  const int bid0 = blockIdx.x;
  const int bid = (bid0 & 7) * 256 + (bid0 >> 3);   // XCD swizzle (2048%8==0)
  const int qc = bid & 31;
  const int h  = (bid >> 5) & (H_ - 1);
  const int b  = bid >> 9;
  const int bh = b * H_ + h;

  const int tid = threadIdx.x;
  const int w = tid >> 6, lane = tid & 63;
  const int l15 = lane & 15, lg = lane >> 4;
  const int qrow0 = qc * 128 + w * 32;

  // Q as B-operand: col=q=l15, k=d=lg*8+i (same register content as A layout)
  short8_t qf[2][2];
#pragma unroll
  for (int s = 0; s < 2; ++s)
#pragma unroll
    for (int kc = 0; kc < 2; ++kc)
      qf[s][kc] = *(const short8_t*)(qb + ((size_t)bh * L_ + qrow0 + s * 16 + l15) * D_ + kc * 32 + lg * 8);

  f32x4 O[2][4];
#pragma unroll
  for (int s = 0; s < 2; ++s)
#pragma unroll
    for (int nb = 0; nb < 4; ++nb) O[s][nb] = (f32x4){0.f, 0.f, 0.f, 0.f};
  float m0s = -1e30f, m1s = -1e30f;   // running max for q=l15 (per strip)
  float ll0 = 0.f, ll1 = 0.f;         // per-lane partial l for q=l15

  const u16* const kbase = kb + (size_t)bh * L_ * D_;
  const u16* const vbase = vt + (size_t)bh * D_ * L_;

  for (int k0 = 0; k0 < L_; k0 += 128) {
    __syncthreads();
#pragma unroll
    for (int it = 0; it < 4; ++it) {
      const int idx = it * 256 + tid;
      const int rK = idx >> 3, pK = idx & 7;
      glds16(kbase + (size_t)(k0 + rK) * D_ + ((pK ^ (rK & 7)) * 8),
             (char*)&Ks[0][0] + it * 4096 + w * 1024);
      const int rV = idx >> 4, pV = idx & 15;
      glds16(vbase + (size_t)rV * L_ + k0 + ((pV ^ (rV & 7)) * 8),
             (char*)&Vs[0][0] + it * 4096 + w * 1024);
    }
    __syncthreads();

    // QK^T swapped: a_s[kb_][r] = score[key = kb_*16 + lg*4 + r][q = l15]
    f32x4 a0[8], a1[8];
#pragma unroll
    for (int kb_ = 0; kb_ < 8; ++kb_) {
      a0[kb_] = (f32x4){0.f, 0.f, 0.f, 0.f};
      a1[kb_] = (f32x4){0.f, 0.f, 0.f, 0.f};
    }
#pragma unroll
    for (int kb_ = 0; kb_ < 8; ++kb_) {
      const int row = kb_ * 16 + l15;
      const short8_t kf0 = *(const short8_t*)((const char*)&Ks[0][0] + row * 128 + ((lg ^ (row & 7)) * 16));
      const short8_t kf1 = *(const short8_t*)((const char*)&Ks[0][0] + row * 128 + (((4 + lg) ^ (row & 7)) * 16));
      a0[kb_] = __builtin_amdgcn_mfma_f32_16x16x32_bf16(kf0, qf[0][0], a0[kb_], 0, 0, 0);
      a0[kb_] = __builtin_amdgcn_mfma_f32_16x16x32_bf16(kf1, qf[0][1], a0[kb_], 0, 0, 0);
      a1[kb_] = __builtin_amdgcn_mfma_f32_16x16x32_bf16(kf0, qf[1][0], a1[kb_], 0, 0, 0);
      a1[kb_] = __builtin_amdgcn_mfma_f32_16x16x32_bf16(kf1, qf[1][1], a1[kb_], 0, 0, 0);
    }

    short8_t pa0[4], pa1[4];

    // ---- strip macro: softmax + P pack/write + A-frag read ----
#define STRIP(A, MS, LLS, OS, PA)                                              \
    {                                                                          \
      f32x4 mx = A[0];                                                         \
      _Pragma("unroll")                                                        \
      for (int kb_ = 1; kb_ < 8; ++kb_) {                                      \
        _Pragma("unroll")                                                      \
        for (int r = 0; r < 4; ++r) mx[r] = fmaxf(mx[r], A[kb_][r]);           \
      }                                                                        \
      float rm = fmaxf(fmaxf(mx[0], mx[1]), fmaxf(mx[2], mx[3]));              \
      rm = fmaxf(rm, __shfl_xor(rm, 16));                                      \
      rm = fmaxf(rm, __shfl_xor(rm, 32));                                      \
      if (__any(rm > MS + 8.0f)) {                                             \
        const float mn = fmaxf(MS, rm);                                        \
        const float corr = exp2f(MS - mn);                                     \
        MS = mn;                                                               \
        LLS *= corr;                                                           \
        _Pragma("unroll")                                                      \
        for (int r = 0; r < 4; ++r) {                                          \
          const float cr = __shfl(corr, 4 * lg + r);                           \
          _Pragma("unroll")                                                    \
          for (int nb = 0; nb < 4; ++nb) OS[nb][r] *= cr;                      \
        }                                                                      \
      }                                                                        \
      _Pragma("unroll")                                                        \
      for (int kb_ = 0; kb_ < 8; ++kb_) {                                      \
        const float p0 = exp2f(A[kb_][0] - MS);                                \
        const float p1 = exp2f(A[kb_][1] - MS);                                \
        const float p2 = exp2f(A[kb_][2] - MS);                                \
        const float p3 = exp2f(A[kb_][3] - MS);                                \
        LLS += (p0 + p1) + (p2 + p3);                                          \
        short4_t pw;                                                           \
        pw[0] = (short)f2bf_u(p0); pw[1] = (short)f2bf_u(p1);                  \
        pw[2] = (short)f2bf_u(p2); pw[3] = (short)f2bf_u(p3);                  \
        *(short4_t*)&Pt[w][l15][16 * kb_ + 4 * lg] = pw;                       \
      }                                                                        \
      _Pragma("unroll")                                                        \
      for (int kc = 0; kc < 4; ++kc)                                           \
        PA[kc] = *(const short8_t*)&Pt[w][l15][kc * 32 + lg * 8];              \
    }

    STRIP(a0, m0s, ll0, O[0], pa0)
    STRIP(a1, m1s, ll1, O[1], pa1)
#undef STRIP

    // PV: B-frag col = d = nb*16+l15, k = key = kc*32+lg*8+i
#pragma unroll
    for (int nb = 0; nb < 4; ++nb) {
      const int row = nb * 16 + l15;
#pragma unroll
      for (int kc = 0; kc < 4; ++kc) {
        const short8_t vf = *(const short8_t*)((const char*)&Vs[0][0] + row * 256 + (((kc * 4 + lg) ^ (row & 7)) * 16));
        O[0][nb] = __builtin_amdgcn_mfma_f32_16x16x32_bf16(pa0[kc], vf, O[0][nb], 0, 0, 0);
        O[1][nb] = __builtin_amdgcn_mfma_f32_16x16x32_bf16(pa1[kc], vf, O[1][nb], 0, 0, 0);
      }
    }
  }

  // epilogue: reduce ll across lg-group, broadcast 1/l, write bf16 hi/lo ctx
#pragma unroll
  for (int s = 0; s < 2; ++s) {
    float t = s ? ll1 : ll0;
    t += __shfl_xor(t, 16);
    t += __shfl_xor(t, 32);
    const float inv = 1.0f / t;
#pragma unroll
    for (int r = 0; r < 4; ++r) {
      const float invr = __shfl(inv, 4 * lg + r);
      const int row = qrow0 + s * 16 + lg * 4 + r;
      const size_t base = ((size_t)b * L_ + row) * C_ + h * D_ + l15;
#pragma unroll
      for (int nb = 0; nb < 4; ++nb) {
        const float v = O[s][nb][r] * invr;
        const u16 hv = f2bf_u(v);
        ch[base + nb * 16] = hv;
        cl[base + nb * 16] = f2bf_u(v - bf2f_u(hv));
      }
    }
  }
}

// ---------------------------------------------------------------------------
// ws layout (208MB):
// [0,32)    qb bf16
// [32,64)   kb bf16
// [64,96)   vb bf16
// [96,128)  vt bf16 (V^T)
// [128,160) xh  | reused after QKV GEMM: ch (ctx hi, written by attn)
// [160,192) xl  | reused: cl (ctx lo)
// [192,208) Wqkv hi/lo, Wproj hi/lo
// ---------------------------------------------------------------------------
extern "C" void kernel_launch(void* const* d_in, const int* in_sizes, int n_in,
                              void* d_out, int out_size, void* d_ws, size_t ws_size,
                              hipStream_t stream) {
  const float* x       = (const float*)d_in[0];
  const float* W_qkv   = (const float*)d_in[1];
  const float* q_scale = (const float*)d_in[2];
  const float* k_scale = (const float*)d_in[3];
  const float* W_proj  = (const float*)d_in[4];
  const float* b_proj  = (const float*)d_in[5];
  const float* cosT    = (const float*)d_in[6];
  const float* sinT    = (const float*)d_in[7];
  float* out = (float*)d_out;

  const int M = B_ * L_;                    // 16384
  const size_t NBLH = (size_t)M * C_;       // 16M elements

  u16* qb = (u16*)d_ws;
  u16* kb = qb + NBLH;
  u16* vb = kb + NBLH;
  u16* vt = vb + NBLH;
  u16* xh = (u16*)((char*)d_ws + (size_t)128 * 1024 * 1024);
  u16* xl = xh + NBLH;
  u16* wqh = (u16*)((char*)d_ws + (size_t)192 * 1024 * 1024);
  u16* wql = wqh + (size_t)C3_ * C_;
  u16* wph = wql + (size_t)C3_ * C_;
  u16* wpl = wph + (size_t)C_ * C_;
  u16* ch = xh;                             // ctx hi/lo reuse xh/xl space
  u16* cl = xl;

  // 1) splits
  split_kernel<<<2048, 256, 0, stream>>>(x, xh, xl, (int)(NBLH / 4));
  split_kernel<<<512, 256, 0, stream>>>(W_qkv, wqh, wql, C3_ * C_ / 4);
  split_kernel<<<512, 256, 0, stream>>>(W_proj, wph, wpl, C_ * C_ / 4);
  // 2) qkv = x @ W_qkv^T -> bf16 head-major qb/kb/vb
  {
    dim3 grid(C3_ / 128, M / 128);
    gemm_bx3_kernel<1><<<grid, 256, 0, stream>>>(xh, xl, wqh, wql, nullptr,
                                                 nullptr, qb, kb, vb, M, C3_, C_);
  }
  // 3) RMSNorm + RoPE in place (scale folded into q)
  normrope2_kernel<<<2 * B_ * H_ * L_ / 4, 256, 0, stream>>>(qb, kb, q_scale, k_scale, cosT, sinT);
  // 4) V transpose
  {
    dim3 grid(L_ / 64, B_ * H_);
    vtrans_kernel<<<grid, 256, 0, stream>>>(vb, vt);
  }
  // 5) attention -> ch/cl bf16 hi/lo (ctx split fused into epilogue)
  attn3_kernel<<<B_ * H_ * (L_ / 128), 256, 0, stream>>>(qb, kb, vt, ch, cl);
  // 6) out = ctx @ W_proj^T + b_proj
  {
    dim3 grid(C_ / 128, M / 128);
    gemm_bx3_kernel<0><<<grid, 256, 0, stream>>>(ch, cl, wph, wpl, b_proj, out,
                                                 nullptr, nullptr, nullptr, M, C_, C_);
  }
}